// Round 9
// baseline (115.654 us; speedup 1.0000x reference)
//
#include <hip/hip_runtime.h>
#include <hip/hip_bf16.h>

#define NN 50000
#define NE 800000
#define NF 128
#define NH 64
#define LRELU 0.05f
#define NTILES (NN / 16)                    // 3125 (exact)
#define SLOT 64                             // fixed per-node segment capacity

typedef __attribute__((ext_vector_type(8))) short bf16x8;  // 8 bf16 = 4 VGPR
typedef __attribute__((ext_vector_type(4))) float f32x4;
typedef __attribute__((ext_vector_type(4))) unsigned int u32x4;

static __device__ inline short f2bf(float f) {
    __hip_bfloat16 h = __float2bfloat16(f);
    return *reinterpret_cast<short*>(&h);
}

// ---------------------------------------------------------------------------
// K0: build Bt[80][128] bf16: rows 0..63 = W_fc^T, row 64 = (W@a1)^T,
// row 65 = (W@a2)^T, rows 66..79 = 0.
// ---------------------------------------------------------------------------
__global__ __launch_bounds__(128) void k0_build_bt(
    const float* __restrict__ W, const float* __restrict__ a_w,
    __hip_bfloat16* __restrict__ Bt)
{
    const int c = blockIdx.x;     // output column (0..79)
    const int k = threadIdx.x;    // input feature (0..127)
    float v = 0.f;
    if (c < NH) {
        v = W[k * NH + c];
    } else if (c == NH) {
        #pragma unroll 8
        for (int h = 0; h < NH; ++h) v = fmaf(W[k * NH + h], a_w[h], v);
    } else if (c == NH + 1) {
        #pragma unroll 8
        for (int h = 0; h < NH; ++h) v = fmaf(W[k * NH + h], a_w[NH + h], v);
    }
    Bt[c * NF + k] = __float2bfloat16(v);
}

// ---------------------------------------------------------------------------
// K1: MFMA GEMM: [z16 | s_dst | s_src] = x @ Bt^T.
// 1 wave = 16 rows x 80 cols; B fragments in registers; no LDS, no barriers.
// Also zeroes counts[] (free: one store per thread before the tile guard).
// ---------------------------------------------------------------------------
__global__ __launch_bounds__(256) void k1_gemm(
    const float* __restrict__ x, const __hip_bfloat16* __restrict__ Bt,
    __hip_bfloat16* __restrict__ z16,
    float* __restrict__ s_dst, float* __restrict__ s_src,
    int* __restrict__ counts)
{
    const int gid = blockIdx.x * 256 + threadIdx.x;
    if (gid < NN) counts[gid] = 0;          // zero cursor array (replaces memset)

    const int wave = threadIdx.x >> 6, lane = threadIdx.x & 63;
    const int tile = blockIdx.x * 4 + wave;     // 16-row tile id
    if (tile >= NTILES) return;
    const int r0   = tile * 16;
    const int lrow = lane & 15;                 // row (A) / col (B,C)
    const int lgrp = lane >> 4;                 // k-group

    bf16x8 bfrag[5][4];
    #pragma unroll
    for (int n = 0; n < 5; ++n)
        #pragma unroll
        for (int t = 0; t < 4; ++t)
            bfrag[n][t] = *(const bf16x8*)&Bt[(n * 16 + lrow) * NF + t * 32 + lgrp * 8];

    bf16x8 afrag[4];
    const float* xrow = x + (size_t)(r0 + lrow) * NF + lgrp * 8;
    #pragma unroll
    for (int t = 0; t < 4; ++t) {
        f32x4 u = *(const f32x4*)(xrow + t * 32);
        f32x4 v = *(const f32x4*)(xrow + t * 32 + 4);
        bf16x8 a;
        #pragma unroll
        for (int j = 0; j < 4; ++j) { a[j] = f2bf(u[j]); a[4 + j] = f2bf(v[j]); }
        afrag[t] = a;
    }

    f32x4 acc[5] = {};
    #pragma unroll
    for (int t = 0; t < 4; ++t)
        #pragma unroll
        for (int n = 0; n < 5; ++n)
            acc[n] = __builtin_amdgcn_mfma_f32_16x16x32_bf16(afrag[t], bfrag[n][t], acc[n], 0, 0, 0);

    // C layout: col = lane&15, row = (lane>>4)*4 + reg
    #pragma unroll
    for (int n = 0; n < 4; ++n)
        #pragma unroll
        for (int r = 0; r < 4; ++r)
            z16[(size_t)(r0 + lgrp * 4 + r) * NH + n * 16 + lrow] = __float2bfloat16(acc[n][r]);

    #pragma unroll
    for (int r = 0; r < 4; ++r) {
        const int orow = r0 + lgrp * 4 + r;
        if (lrow == 0)      s_dst[orow] = acc[4][r];
        else if (lrow == 1) s_src[orow] = acc[4][r];
    }
}

// ---------------------------------------------------------------------------
// K5: 4 edges/thread. h = exp(leakyrelu(sd+ss+b)) -> alpha slot (float4,
// coalesced); cursor = atomicAdd(counts[d]); scatter packed
// {src:u16 | bf16(h):u16} into the node's fixed 64-slot segment.
// All 4 edges' loads/atomics issued independently (4x MLP on the chain).
// ---------------------------------------------------------------------------
__global__ __launch_bounds__(256) void k5_build(
    const int* __restrict__ ei,
    const float* __restrict__ s_dst, const float* __restrict__ s_src,
    const float* __restrict__ a_b,
    int* __restrict__ counts,
    float* __restrict__ halpha, unsigned int* __restrict__ payload)
{
    const int e0 = (blockIdx.x * 256 + threadIdx.x) * 4;
    if (e0 >= NE) return;                       // NE % 4 == 0: no intra-quad tail
    const float b = a_b[0];

    const int4 d4 = *(const int4*)(ei + e0);
    const int4 s4 = *(const int4*)(ei + NE + e0);

    const float sd0 = s_dst[d4.x], sd1 = s_dst[d4.y];
    const float sd2 = s_dst[d4.z], sd3 = s_dst[d4.w];
    const float ss0 = s_src[s4.x], ss1 = s_src[s4.y];
    const float ss2 = s_src[s4.z], ss3 = s_src[s4.w];

    float h0 = sd0 + ss0 + b; h0 = (h0 >= 0.f) ? h0 : LRELU * h0; h0 = expf(h0);
    float h1 = sd1 + ss1 + b; h1 = (h1 >= 0.f) ? h1 : LRELU * h1; h1 = expf(h1);
    float h2 = sd2 + ss2 + b; h2 = (h2 >= 0.f) ? h2 : LRELU * h2; h2 = expf(h2);
    float h3 = sd3 + ss3 + b; h3 = (h3 >= 0.f) ? h3 : LRELU * h3; h3 = expf(h3);

    f32x4 hq = {h0, h1, h2, h3};
    *(f32x4*)(halpha + e0) = hq;

    const int c0 = atomicAdd(&counts[d4.x], 1);
    const int c1 = atomicAdd(&counts[d4.y], 1);
    const int c2 = atomicAdd(&counts[d4.z], 1);
    const int c3 = atomicAdd(&counts[d4.w], 1);

    if (c0 < SLOT) payload[d4.x * SLOT + c0] = (unsigned int)s4.x | ((unsigned int)(unsigned short)f2bf(h0) << 16);
    if (c1 < SLOT) payload[d4.y * SLOT + c1] = (unsigned int)s4.y | ((unsigned int)(unsigned short)f2bf(h1) << 16);
    if (c2 < SLOT) payload[d4.z * SLOT + c2] = (unsigned int)s4.z | ((unsigned int)(unsigned short)f2bf(h2) << 16);
    if (c3 < SLOT) payload[d4.w * SLOT + c3] = (unsigned int)s4.w | ((unsigned int)(unsigned short)f2bf(h3) << 16);
}

// ---------------------------------------------------------------------------
// K6: one wave per node: out[i] = (sum_j h_j * z[src_j]) / hsum; store rinv.
// Wide gathers: 8 lanes per z-row x dwordx4 -> ONE load covers 8 edges (1KB).
// Metadata distributed via ds_bpermute of the preloaded packed payload.
// ---------------------------------------------------------------------------
__global__ __launch_bounds__(256) void k6_aggregate(
    const __hip_bfloat16* __restrict__ z16,
    const int* __restrict__ counts, const unsigned int* __restrict__ payload,
    float* __restrict__ rinv_arr, float* __restrict__ out)
{
    const int wid = (blockIdx.x * 256 + threadIdx.x) >> 6;   // node id
    const int lane = threadIdx.x & 63;
    if (wid >= NN) return;

    int deg = __builtin_amdgcn_readfirstlane(counts[wid]);
    if (deg > SLOT) deg = SLOT;

    const int sub  = lane >> 3;          // edge slot within 8-edge group
    const int col8 = lane & 7;           // col block: cols col8*8 .. col8*8+7
    const char* zb = (const char*)z16;

    unsigned int pv = 0;
    if (lane < deg) pv = payload[wid * SLOT + lane];
    float hs = __uint_as_float(pv & 0xffff0000u);

    float acc[8] = {0.f, 0.f, 0.f, 0.f, 0.f, 0.f, 0.f, 0.f};

    const int gmax = (deg + 7) >> 3;
    for (int g = 0; g < gmax; ++g) {
        // lane grabs packed value of slot (g*8 + sub)
        const unsigned int pg = (unsigned int)__builtin_amdgcn_ds_bpermute(
            ((g << 3) | sub) << 2, (int)pv);
        const float hg = __uint_as_float(pg & 0xffff0000u);   // bf16 h (0 if pad)
        const unsigned int sg = pg & 0xffffu;                 // src node
        const u32x4 q = *(const u32x4*)(zb + ((size_t)(sg << 7) | (col8 << 4)));
        #pragma unroll
        for (int i = 0; i < 4; ++i) {
            acc[2*i]   = fmaf(hg, __uint_as_float(q[i] << 16),        acc[2*i]);
            acc[2*i+1] = fmaf(hg, __uint_as_float(q[i] & 0xffff0000u), acc[2*i+1]);
        }
    }

    // reduce acc across the 8 sub-groups (lanes sharing col8): strides 8,16,32
    #pragma unroll
    for (int off = 8; off <= 32; off <<= 1)
        #pragma unroll
        for (int i = 0; i < 8; ++i) acc[i] += __shfl_xor(acc[i], off, 64);

    // full-wave hsum reduce
    #pragma unroll
    for (int off = 32; off > 0; off >>= 1) hs += __shfl_xor(hs, off, 64);
    const float rinv = (deg > 0) ? 1.f / hs : 0.f;
    if (lane == 0) rinv_arr[wid] = rinv;

    if (lane < 8) {                       // lane l owns cols l*8 .. l*8+7
        f32x4 o0 = {acc[0] * rinv, acc[1] * rinv, acc[2] * rinv, acc[3] * rinv};
        f32x4 o1 = {acc[4] * rinv, acc[5] * rinv, acc[6] * rinv, acc[7] * rinv};
        float* op = out + (size_t)wid * NH + lane * 8;
        *(f32x4*)op       = o0;
        *(f32x4*)(op + 4) = o1;
    }
}

// ---------------------------------------------------------------------------
// K7: alpha[e] = h[e] * rinv[dst[e]], 4 edges/thread — float4 in-place over
// the h values; coalesced except the tiny L2-resident rinv gather.
// ---------------------------------------------------------------------------
__global__ __launch_bounds__(256) void k7_alpha(
    const int* __restrict__ ei, const float* __restrict__ rinv_arr,
    float* __restrict__ alpha)
{
    const int e0 = (blockIdx.x * 256 + threadIdx.x) * 4;
    if (e0 >= NE) return;
    const int4 d4 = *(const int4*)(ei + e0);
    f32x4 a = *(const f32x4*)(alpha + e0);
    a[0] *= rinv_arr[d4.x];
    a[1] *= rinv_arr[d4.y];
    a[2] *= rinv_arr[d4.z];
    a[3] *= rinv_arr[d4.w];
    *(f32x4*)(alpha + e0) = a;
}

// ---------------------------------------------------------------------------
extern "C" void kernel_launch(void* const* d_in, const int* in_sizes, int n_in,
                              void* d_out, int out_size, void* d_ws, size_t ws_size,
                              hipStream_t stream) {
    const float* x   = (const float*)d_in[0];
    const int*   ei  = (const int*)d_in[1];   // [2*E]: row0 = dst, row1 = src
    const float* W   = (const float*)d_in[2];
    const float* a_w = (const float*)d_in[3];
    const float* a_b = (const float*)d_in[4];

    float* out   = (float*)d_out;                     // [N*64]
    float* alpha = out + (size_t)NN * NH;             // [E]  (h, then alpha)

    // workspace layout (~20 MB)
    __hip_bfloat16* z16 = (__hip_bfloat16*)d_ws;      // [N*64] 6.4 MB
    float* s_dst  = (float*)(z16 + (size_t)NN * NH);  // [N]
    float* s_src  = s_dst + NN;                       // [N]
    float* rinv   = s_src + NN;                       // [N]
    int* counts   = (int*)(rinv + NN);                // [N]
    unsigned int* payload = (unsigned int*)(counts + NN); // [N*64] 12.8 MB
    __hip_bfloat16* Bt = (__hip_bfloat16*)(payload + (size_t)NN * SLOT); // 20 KB

    k0_build_bt <<<80, 128, 0, stream>>>(W, a_w, Bt);
    k1_gemm     <<<(NTILES + 3) / 4, 256, 0, stream>>>(x, Bt, z16, s_dst, s_src, counts);
    k5_build    <<<(NE / 4 + 255) / 256, 256, 0, stream>>>(ei, s_dst, s_src, a_b, counts, alpha, payload);
    k6_aggregate<<<(NN * 64 + 255) / 256, 256, 0, stream>>>(z16, counts, payload, rinv, out);
    k7_alpha    <<<(NE / 4 + 255) / 256, 256, 0, stream>>>(ei, rinv, alpha);
}

// Round 10
// 95.755 us; speedup vs baseline: 1.2078x; 1.2078x over previous
//
#include <hip/hip_runtime.h>
#include <hip/hip_bf16.h>

#define NN 50000
#define NE 800000
#define NF 128
#define NH 64
#define LRELU 0.05f
#define NTILES (NN / 16)                    // 3125 (exact)
#define SLOT 64                             // per-node capacity (max deg ~40)
#define BKT 32                              // nodes per bucket
#define NB ((NN + BKT - 1) / BKT)           // 1563 buckets
#define KB 128                              // edge partition blocks
#define EPB (NE / KB)                       // 6250 edges per block (exact)

typedef __attribute__((ext_vector_type(8))) short bf16x8;  // 8 bf16 = 4 VGPR
typedef __attribute__((ext_vector_type(4))) float f32x4;
typedef __attribute__((ext_vector_type(4))) unsigned int u32x4;

static __device__ inline short f2bf(float f) {
    __hip_bfloat16 h = __float2bfloat16(f);
    return *reinterpret_cast<short*>(&h);
}

// ---------------------------------------------------------------------------
// K0: Bt[80][128] bf16: rows 0..63 = W^T, 64 = (W@a1)^T, 65 = (W@a2)^T, pad 0.
// ---------------------------------------------------------------------------
__global__ __launch_bounds__(128) void k0_build_bt(
    const float* __restrict__ W, const float* __restrict__ a_w,
    __hip_bfloat16* __restrict__ Bt)
{
    const int c = blockIdx.x, k = threadIdx.x;
    float v = 0.f;
    if (c < NH) {
        v = W[k * NH + c];
    } else if (c == NH) {
        #pragma unroll 8
        for (int h = 0; h < NH; ++h) v = fmaf(W[k * NH + h], a_w[h], v);
    } else if (c == NH + 1) {
        #pragma unroll 8
        for (int h = 0; h < NH; ++h) v = fmaf(W[k * NH + h], a_w[NH + h], v);
    }
    Bt[c * NF + k] = __float2bfloat16(v);
}

// ---------------------------------------------------------------------------
// K1: MFMA GEMM: [z16 | s_dst | s_src] = x @ Bt^T. 1 wave = 16 rows x 80 cols.
// ---------------------------------------------------------------------------
__global__ __launch_bounds__(256) void k1_gemm(
    const float* __restrict__ x, const __hip_bfloat16* __restrict__ Bt,
    __hip_bfloat16* __restrict__ z16,
    float* __restrict__ s_dst, float* __restrict__ s_src)
{
    const int wave = threadIdx.x >> 6, lane = threadIdx.x & 63;
    const int tile = blockIdx.x * 4 + wave;
    if (tile >= NTILES) return;
    const int r0   = tile * 16;
    const int lrow = lane & 15;
    const int lgrp = lane >> 4;

    bf16x8 bfrag[5][4];
    #pragma unroll
    for (int n = 0; n < 5; ++n)
        #pragma unroll
        for (int t = 0; t < 4; ++t)
            bfrag[n][t] = *(const bf16x8*)&Bt[(n * 16 + lrow) * NF + t * 32 + lgrp * 8];

    bf16x8 afrag[4];
    const float* xrow = x + (size_t)(r0 + lrow) * NF + lgrp * 8;
    #pragma unroll
    for (int t = 0; t < 4; ++t) {
        f32x4 u = *(const f32x4*)(xrow + t * 32);
        f32x4 v = *(const f32x4*)(xrow + t * 32 + 4);
        bf16x8 a;
        #pragma unroll
        for (int j = 0; j < 4; ++j) { a[j] = f2bf(u[j]); a[4 + j] = f2bf(v[j]); }
        afrag[t] = a;
    }

    f32x4 acc[5] = {};
    #pragma unroll
    for (int t = 0; t < 4; ++t)
        #pragma unroll
        for (int n = 0; n < 5; ++n)
            acc[n] = __builtin_amdgcn_mfma_f32_16x16x32_bf16(afrag[t], bfrag[n][t], acc[n], 0, 0, 0);

    #pragma unroll
    for (int n = 0; n < 4; ++n)
        #pragma unroll
        for (int r = 0; r < 4; ++r)
            z16[(size_t)(r0 + lgrp * 4 + r) * NH + n * 16 + lrow] = __float2bfloat16(acc[n][r]);

    #pragma unroll
    for (int r = 0; r < 4; ++r) {
        const int orow = r0 + lgrp * 4 + r;
        if (lrow == 0)      s_dst[orow] = acc[4][r];
        else if (lrow == 1) s_src[orow] = acc[4][r];
    }
}

// ---------------------------------------------------------------------------
// KA: per-(block,bucket) histogram of dst via LDS; coalesced matrix write.
// ---------------------------------------------------------------------------
__global__ __launch_bounds__(512) void kA_count(
    const int* __restrict__ ei, unsigned* __restrict__ Cmat)
{
    __shared__ unsigned hist[NB];
    for (int i = threadIdx.x; i < NB; i += 512) hist[i] = 0;
    __syncthreads();
    const int base = blockIdx.x * EPB;
    for (int i = threadIdx.x; i < EPB; i += 512)
        atomicAdd(&hist[ei[base + i] >> 5], 1u);
    __syncthreads();
    for (int i = threadIdx.x; i < NB; i += 512)
        Cmat[(size_t)blockIdx.x * NB + i] = hist[i];
}

// ---------------------------------------------------------------------------
// KB1: per-bucket exclusive scan down the 128-block column; totals out.
// Overwrites Cmat with per-(block,bucket) starts. One wave per bucket.
// ---------------------------------------------------------------------------
__global__ __launch_bounds__(256) void kB1_colscan(
    unsigned* __restrict__ Cmat, unsigned* __restrict__ totals)
{
    const int b = blockIdx.x * 4 + (threadIdx.x >> 6);
    const int lane = threadIdx.x & 63;
    if (b >= NB) return;
    const unsigned v0 = Cmat[(size_t)lane * NB + b];
    const unsigned v1 = Cmat[(size_t)(64 + lane) * NB + b];
    unsigned s0 = v0, s1 = v1;
    #pragma unroll
    for (int o = 1; o < 64; o <<= 1) {
        unsigned t0 = __shfl_up(s0, o, 64);
        unsigned t1 = __shfl_up(s1, o, 64);
        if (lane >= o) { s0 += t0; s1 += t1; }
    }
    const unsigned tot0 = __shfl(s0, 63, 64);
    const unsigned tot1 = __shfl(s1, 63, 64);
    Cmat[(size_t)lane * NB + b]        = s0 - v0;
    Cmat[(size_t)(64 + lane) * NB + b] = tot0 + s1 - v1;
    if (lane == 0) totals[b] = tot0 + tot1;
}

// ---------------------------------------------------------------------------
// KB2: exclusive scan of NB bucket totals -> bucket bases (1 block, 2/thread).
// ---------------------------------------------------------------------------
__global__ __launch_bounds__(1024) void kB2_scan(
    const unsigned* __restrict__ totals, unsigned* __restrict__ bbase)
{
    __shared__ unsigned wsum[16];
    const int t = threadIdx.x, lane = t & 63, wave = t >> 6;
    const unsigned a0 = (2 * t     < NB) ? totals[2 * t]     : 0;
    const unsigned a1 = (2 * t + 1 < NB) ? totals[2 * t + 1] : 0;
    const unsigned p = a0 + a1;
    unsigned s = p;
    #pragma unroll
    for (int o = 1; o < 64; o <<= 1) {
        unsigned q = __shfl_up(s, o, 64);
        if (lane >= o) s += q;
    }
    if (lane == 63) wsum[wave] = s;
    __syncthreads();
    if (t < 64) {
        unsigned w = (lane < 16) ? wsum[lane] : 0;
        #pragma unroll
        for (int o = 1; o < 16; o <<= 1) {
            unsigned q = __shfl_up(w, o, 64);
            if (lane >= o) w += q;
        }
        if (lane < 16) wsum[lane] = w;
    }
    __syncthreads();
    const unsigned wb = (wave > 0) ? wsum[wave - 1] : 0;
    const unsigned ex = wb + s - p;
    if (2 * t     < NB) bbase[2 * t]     = ex;
    if (2 * t + 1 < NB) bbase[2 * t + 1] = ex + a0;
}

// ---------------------------------------------------------------------------
// KC: partition scatter — rec {src:u16 | dlocal:u5} at deterministic position
// bbase[b] + start[k][b] + LDS-rank. No global atomics; writes cluster ~16B.
// ---------------------------------------------------------------------------
__global__ __launch_bounds__(512) void kC_scatter(
    const int* __restrict__ ei, const unsigned* __restrict__ Cmat,
    const unsigned* __restrict__ bbase, unsigned* __restrict__ recs)
{
    __shared__ unsigned hist[NB];
    for (int i = threadIdx.x; i < NB; i += 512) hist[i] = 0;
    __syncthreads();
    const int base = blockIdx.x * EPB;
    for (int i = threadIdx.x; i < EPB; i += 512) {
        const int d = ei[base + i];
        const int s = ei[NE + base + i];
        const int b = d >> 5;
        const unsigned r = atomicAdd(&hist[b], 1u);
        const unsigned pos = bbase[b] + Cmat[(size_t)blockIdx.x * NB + b] + r;
        recs[pos] = (unsigned)s | ((unsigned)(d & 31) << 16);
    }
}

// ---------------------------------------------------------------------------
// KD: one block per bucket (32 nodes). Stage: read recs (coalesced), compute
// h = exp(lrelu(sd+ss+b)), bin {src,bf16(h)} into LDS. Aggregate: per-wave
// k6-style wide z-gathers (8 lanes x dwordx4 per row); out + rinv writes.
// ---------------------------------------------------------------------------
__global__ __launch_bounds__(256) void kD_aggregate(
    const __hip_bfloat16* __restrict__ z16,
    const float* __restrict__ s_dst, const float* __restrict__ s_src,
    const float* __restrict__ a_b,
    const unsigned* __restrict__ recs, const unsigned* __restrict__ totals,
    const unsigned* __restrict__ bbase,
    float* __restrict__ rinv_arr, float* __restrict__ out)
{
    __shared__ unsigned bins[BKT * SLOT];   // 8 KB
    __shared__ unsigned lcnt[BKT];
    __shared__ float    sdl[BKT];
    const int bkt = blockIdx.x;
    const int tid = threadIdx.x;
    const int n0  = bkt * BKT;

    if (tid < BKT) {
        lcnt[tid] = 0;
        sdl[tid] = (n0 + tid < NN) ? s_dst[n0 + tid] : 0.f;
    }
    __syncthreads();

    const unsigned tot = totals[bkt];
    const unsigned rb  = bbase[bkt];
    const float bias   = a_b[0];

    for (unsigned i = tid; i < tot; i += 256) {
        const unsigned rec = recs[rb + i];
        const unsigned src = rec & 0xffffu;
        const unsigned dl  = (rec >> 16) & 31u;
        float h = sdl[dl] + s_src[src] + bias;
        h = (h >= 0.f) ? h : LRELU * h;
        h = expf(h);
        const unsigned r = atomicAdd(&lcnt[dl], 1u);
        if (r < SLOT)
            bins[dl * SLOT + r] = src | ((unsigned)(unsigned short)f2bf(h) << 16);
    }
    __syncthreads();

    const int wave = tid >> 6, lane = tid & 63;
    const int sub  = lane >> 3, col8 = lane & 7;
    const char* zb = (const char*)z16;

    for (int dl = wave; dl < BKT; dl += 4) {
        const int node = n0 + dl;
        if (node >= NN) break;
        int deg = (int)__builtin_amdgcn_readfirstlane(lcnt[dl]);
        if (deg > SLOT) deg = SLOT;

        unsigned pv = (lane < deg) ? bins[dl * SLOT + lane] : 0u;
        float hs = __uint_as_float(pv & 0xffff0000u);
        float acc[8] = {0.f, 0.f, 0.f, 0.f, 0.f, 0.f, 0.f, 0.f};

        const int gmax = (deg + 7) >> 3;
        for (int g = 0; g < gmax; ++g) {
            const unsigned pg = (unsigned)__builtin_amdgcn_ds_bpermute(
                ((g << 3) | sub) << 2, (int)pv);
            const float hg = __uint_as_float(pg & 0xffff0000u);
            const unsigned sg = pg & 0xffffu;
            const u32x4 q = *(const u32x4*)(zb + ((size_t)(sg << 7) | (col8 << 4)));
            #pragma unroll
            for (int i = 0; i < 4; ++i) {
                acc[2*i]   = fmaf(hg, __uint_as_float(q[i] << 16),         acc[2*i]);
                acc[2*i+1] = fmaf(hg, __uint_as_float(q[i] & 0xffff0000u), acc[2*i+1]);
            }
        }

        #pragma unroll
        for (int off = 8; off <= 32; off <<= 1)
            #pragma unroll
            for (int i = 0; i < 8; ++i) acc[i] += __shfl_xor(acc[i], off, 64);

        #pragma unroll
        for (int off = 32; off > 0; off >>= 1) hs += __shfl_xor(hs, off, 64);
        const float rinv = (deg > 0) ? 1.f / hs : 0.f;
        if (lane == 0) rinv_arr[node] = rinv;

        if (lane < 8) {
            f32x4 o0 = {acc[0] * rinv, acc[1] * rinv, acc[2] * rinv, acc[3] * rinv};
            f32x4 o1 = {acc[4] * rinv, acc[5] * rinv, acc[6] * rinv, acc[7] * rinv};
            float* op = out + (size_t)node * NH + lane * 8;
            *(f32x4*)op       = o0;
            *(f32x4*)(op + 4) = o1;
        }
    }
}

// ---------------------------------------------------------------------------
// K7: alpha[e] = exp(lrelu(sd+ss+b)) * rinv[dst] — f32-exact h, coalesced
// write; 3 small L2-resident gathers per edge.
// ---------------------------------------------------------------------------
__global__ __launch_bounds__(256) void k7_alpha(
    const int* __restrict__ ei,
    const float* __restrict__ s_dst, const float* __restrict__ s_src,
    const float* __restrict__ a_b, const float* __restrict__ rinv_arr,
    float* __restrict__ alpha)
{
    const int e = blockIdx.x * 256 + threadIdx.x;
    if (e >= NE) return;
    const int d = ei[e];
    const int s = ei[NE + e];
    float h = s_dst[d] + s_src[s] + a_b[0];
    h = (h >= 0.f) ? h : LRELU * h;
    alpha[e] = expf(h) * rinv_arr[d];
}

// ---------------------------------------------------------------------------
extern "C" void kernel_launch(void* const* d_in, const int* in_sizes, int n_in,
                              void* d_out, int out_size, void* d_ws, size_t ws_size,
                              hipStream_t stream) {
    const float* x   = (const float*)d_in[0];
    const int*   ei  = (const int*)d_in[1];   // [2*E]: row0 = dst, row1 = src
    const float* W   = (const float*)d_in[2];
    const float* a_w = (const float*)d_in[3];
    const float* a_b = (const float*)d_in[4];

    float* out   = (float*)d_out;                     // [N*64]
    float* alpha = out + (size_t)NN * NH;             // [E]

    // workspace layout (~11 MB)
    __hip_bfloat16* z16 = (__hip_bfloat16*)d_ws;          // [N*64]   6.4 MB
    __hip_bfloat16* Bt  = z16 + (size_t)NN * NH;          // [80*128] 20 KB
    float* s_dst  = (float*)(Bt + 80 * NF);               // [N]
    float* s_src  = s_dst + NN;                           // [N]
    float* rinv   = s_src + NN;                           // [N]
    unsigned* totals = (unsigned*)(rinv + NN);            // [NB]
    unsigned* bbase  = totals + NB;                       // [NB]
    unsigned* Cmat   = bbase + NB;                        // [KB*NB] 800 KB
    unsigned* recs   = Cmat + (size_t)KB * NB;            // [E]     3.2 MB

    k0_build_bt <<<80, 128, 0, stream>>>(W, a_w, Bt);
    k1_gemm     <<<(NTILES + 3) / 4, 256, 0, stream>>>(x, Bt, z16, s_dst, s_src);
    kA_count    <<<KB, 512, 0, stream>>>(ei, Cmat);
    kB1_colscan <<<(NB + 3) / 4, 256, 0, stream>>>(Cmat, totals);
    kB2_scan    <<<1, 1024, 0, stream>>>(totals, bbase);
    kC_scatter  <<<KB, 512, 0, stream>>>(ei, Cmat, bbase, recs);
    kD_aggregate<<<NB, 256, 0, stream>>>(z16, s_dst, s_src, a_b, recs, totals, bbase, rinv, out);
    k7_alpha    <<<(NE + 255) / 256, 256, 0, stream>>>(ei, s_dst, s_src, a_b, rinv, alpha);
}

// Round 11
// 83.559 us; speedup vs baseline: 1.3841x; 1.1460x over previous
//
#include <hip/hip_runtime.h>
#include <hip/hip_bf16.h>

#define NN 50000
#define NE 800000
#define NF 128
#define NH 64
#define LRELU 0.05f
#define NTILES (NN / 16)                    // 3125 (exact)
#define SLOT 64                             // per-node capacity (max deg ~40)
#define BKT 32                              // nodes per bucket
#define NB ((NN + BKT - 1) / BKT)           // 1563 buckets
#define CAP 704                             // per-bucket capacity (load ~512+8.5 sigma)
#define KB 64                               // partition blocks
#define EPB (NE / KB)                       // 12500 edges per block (exact)

typedef __attribute__((ext_vector_type(8))) short bf16x8;  // 8 bf16 = 4 VGPR
typedef __attribute__((ext_vector_type(4))) float f32x4;
typedef __attribute__((ext_vector_type(4))) unsigned int u32x4;

static __device__ inline short f2bf(float f) {
    __hip_bfloat16 h = __float2bfloat16(f);
    return *reinterpret_cast<short*>(&h);
}

// ---------------------------------------------------------------------------
// K0: Bt[80][128] bf16: rows 0..63 = W^T, 64 = (W@a1)^T, 65 = (W@a2)^T, pad 0.
// Also zeroes the per-bucket cursor array (10240 threads >= NB).
// ---------------------------------------------------------------------------
__global__ __launch_bounds__(128) void k0_build_bt(
    const float* __restrict__ W, const float* __restrict__ a_w,
    __hip_bfloat16* __restrict__ Bt, int* __restrict__ cursor)
{
    const int c = blockIdx.x, k = threadIdx.x;
    const int gid = c * 128 + k;
    if (gid < NB) cursor[gid] = 0;

    float v = 0.f;
    if (c < NH) {
        v = W[k * NH + c];
    } else if (c == NH) {
        #pragma unroll 8
        for (int h = 0; h < NH; ++h) v = fmaf(W[k * NH + h], a_w[h], v);
    } else if (c == NH + 1) {
        #pragma unroll 8
        for (int h = 0; h < NH; ++h) v = fmaf(W[k * NH + h], a_w[NH + h], v);
    }
    Bt[c * NF + k] = __float2bfloat16(v);
}

// ---------------------------------------------------------------------------
// K1: MFMA GEMM: [z16 | s_dst | s_src] = x @ Bt^T. 1 wave = 16 rows x 80 cols.
// ---------------------------------------------------------------------------
__global__ __launch_bounds__(256) void k1_gemm(
    const float* __restrict__ x, const __hip_bfloat16* __restrict__ Bt,
    __hip_bfloat16* __restrict__ z16,
    float* __restrict__ s_dst, float* __restrict__ s_src)
{
    const int wave = threadIdx.x >> 6, lane = threadIdx.x & 63;
    const int tile = blockIdx.x * 4 + wave;
    if (tile >= NTILES) return;
    const int r0   = tile * 16;
    const int lrow = lane & 15;
    const int lgrp = lane >> 4;

    bf16x8 bfrag[5][4];
    #pragma unroll
    for (int n = 0; n < 5; ++n)
        #pragma unroll
        for (int t = 0; t < 4; ++t)
            bfrag[n][t] = *(const bf16x8*)&Bt[(n * 16 + lrow) * NF + t * 32 + lgrp * 8];

    bf16x8 afrag[4];
    const float* xrow = x + (size_t)(r0 + lrow) * NF + lgrp * 8;
    #pragma unroll
    for (int t = 0; t < 4; ++t) {
        f32x4 u = *(const f32x4*)(xrow + t * 32);
        f32x4 v = *(const f32x4*)(xrow + t * 32 + 4);
        bf16x8 a;
        #pragma unroll
        for (int j = 0; j < 4; ++j) { a[j] = f2bf(u[j]); a[4 + j] = f2bf(v[j]); }
        afrag[t] = a;
    }

    f32x4 acc[5] = {};
    #pragma unroll
    for (int t = 0; t < 4; ++t)
        #pragma unroll
        for (int n = 0; n < 5; ++n)
            acc[n] = __builtin_amdgcn_mfma_f32_16x16x32_bf16(afrag[t], bfrag[n][t], acc[n], 0, 0, 0);

    #pragma unroll
    for (int n = 0; n < 4; ++n)
        #pragma unroll
        for (int r = 0; r < 4; ++r)
            z16[(size_t)(r0 + lgrp * 4 + r) * NH + n * 16 + lrow] = __float2bfloat16(acc[n][r]);

    #pragma unroll
    for (int r = 0; r < 4; ++r) {
        const int orow = r0 + lgrp * 4 + r;
        if (lrow == 0)      s_dst[orow] = acc[4][r];
        else if (lrow == 1) s_src[orow] = acc[4][r];
    }
}

// ---------------------------------------------------------------------------
// KC: one-kernel partition. Pass 1: LDS histogram of this block's edge range.
// Reserve: ONE global atomicAdd per (block,bucket). Pass 2: scatter
// {src:u16 | dlocal:u5} to recs[bkt*CAP + basel + LDS-rank] — per-block runs
// (~8 recs = 32 B) cluster into sectors; no per-edge global atomics.
// ---------------------------------------------------------------------------
__global__ __launch_bounds__(1024) void kC_partition(
    const int* __restrict__ ei, int* __restrict__ cursor,
    unsigned* __restrict__ recs)
{
    __shared__ unsigned hist[NB];    // 6.25 KB
    __shared__ unsigned basel[NB];   // 6.25 KB
    const int tid = threadIdx.x;
    for (int i = tid; i < NB; i += 1024) hist[i] = 0;
    __syncthreads();

    const int base = blockIdx.x * EPB;
    for (int i = tid; i < EPB; i += 1024)
        atomicAdd(&hist[ei[base + i] >> 5], 1u);
    __syncthreads();

    for (int b = tid; b < NB; b += 1024) {
        const unsigned c = hist[b];
        basel[b] = c ? (unsigned)atomicAdd(&cursor[b], (int)c) : 0u;
        hist[b] = 0;                 // reset for the rank pass
    }
    __syncthreads();

    for (int i = tid; i < EPB; i += 1024) {
        const int d = ei[base + i];
        const int s = ei[NE + base + i];
        const int b = d >> 5;
        const unsigned r = basel[b] + atomicAdd(&hist[b], 1u);
        if (r < CAP)
            recs[(size_t)b * CAP + r] = (unsigned)s | ((unsigned)(d & 31) << 16);
    }
}

// ---------------------------------------------------------------------------
// KD: one block (512 thr) per bucket (32 nodes). Stage: read recs (coalesced),
// h = exp(lrelu(sd+ss+b)), bin {src,bf16(h)} into LDS. Aggregate: per-wave
// wide z-gathers (8 lanes x dwordx4 per row = 8 edges per load); out + rinv.
// ---------------------------------------------------------------------------
__global__ __launch_bounds__(512) void kD_aggregate(
    const __hip_bfloat16* __restrict__ z16,
    const float* __restrict__ s_dst, const float* __restrict__ s_src,
    const float* __restrict__ a_b,
    const unsigned* __restrict__ recs, const int* __restrict__ cursor,
    float* __restrict__ rinv_arr, float* __restrict__ out)
{
    __shared__ unsigned bins[BKT * SLOT];   // 8 KB
    __shared__ unsigned lcnt[BKT];
    __shared__ float    sdl[BKT];
    const int bkt = blockIdx.x;
    const int tid = threadIdx.x;
    const int n0  = bkt * BKT;

    if (tid < BKT) {
        lcnt[tid] = 0;
        sdl[tid] = (n0 + tid < NN) ? s_dst[n0 + tid] : 0.f;
    }
    __syncthreads();

    int tot = cursor[bkt];
    if (tot > CAP) tot = CAP;
    const float bias = a_b[0];

    for (int i = tid; i < tot; i += 512) {
        const unsigned rec = recs[(size_t)bkt * CAP + i];
        const unsigned src = rec & 0xffffu;
        const unsigned dl  = (rec >> 16) & 31u;
        float h = sdl[dl] + s_src[src] + bias;
        h = (h >= 0.f) ? h : LRELU * h;
        h = expf(h);
        const unsigned r = atomicAdd(&lcnt[dl], 1u);
        if (r < SLOT)
            bins[dl * SLOT + r] = src | ((unsigned)(unsigned short)f2bf(h) << 16);
    }
    __syncthreads();

    const int wave = tid >> 6, lane = tid & 63;
    const int sub  = lane >> 3, col8 = lane & 7;
    const char* zb = (const char*)z16;

    for (int dl = wave; dl < BKT; dl += 8) {
        const int node = n0 + dl;
        if (node >= NN) break;
        int deg = (int)__builtin_amdgcn_readfirstlane(lcnt[dl]);
        if (deg > SLOT) deg = SLOT;

        unsigned pv = (lane < deg) ? bins[dl * SLOT + lane] : 0u;
        float hs = __uint_as_float(pv & 0xffff0000u);
        float acc[8] = {0.f, 0.f, 0.f, 0.f, 0.f, 0.f, 0.f, 0.f};

        const int gmax = (deg + 7) >> 3;
        for (int g = 0; g < gmax; ++g) {
            const unsigned pg = (unsigned)__builtin_amdgcn_ds_bpermute(
                ((g << 3) | sub) << 2, (int)pv);
            const float hg = __uint_as_float(pg & 0xffff0000u);
            const unsigned sg = pg & 0xffffu;
            const u32x4 q = *(const u32x4*)(zb + ((size_t)(sg << 7) | (col8 << 4)));
            #pragma unroll
            for (int i = 0; i < 4; ++i) {
                acc[2*i]   = fmaf(hg, __uint_as_float(q[i] << 16),         acc[2*i]);
                acc[2*i+1] = fmaf(hg, __uint_as_float(q[i] & 0xffff0000u), acc[2*i+1]);
            }
        }

        #pragma unroll
        for (int off = 8; off <= 32; off <<= 1)
            #pragma unroll
            for (int i = 0; i < 8; ++i) acc[i] += __shfl_xor(acc[i], off, 64);

        #pragma unroll
        for (int off = 32; off > 0; off >>= 1) hs += __shfl_xor(hs, off, 64);
        const float rinv = (deg > 0) ? 1.f / hs : 0.f;
        if (lane == 0) rinv_arr[node] = rinv;

        if (lane < 8) {
            f32x4 o0 = {acc[0] * rinv, acc[1] * rinv, acc[2] * rinv, acc[3] * rinv};
            f32x4 o1 = {acc[4] * rinv, acc[5] * rinv, acc[6] * rinv, acc[7] * rinv};
            float* op = out + (size_t)node * NH + lane * 8;
            *(f32x4*)op       = o0;
            *(f32x4*)(op + 4) = o1;
        }
    }
}

// ---------------------------------------------------------------------------
// K7: alpha[e] = exp(lrelu(sd+ss+b)) * rinv[dst] — f32-exact h, coalesced
// write; 3 small L2-resident gathers per edge.
// ---------------------------------------------------------------------------
__global__ __launch_bounds__(256) void k7_alpha(
    const int* __restrict__ ei,
    const float* __restrict__ s_dst, const float* __restrict__ s_src,
    const float* __restrict__ a_b, const float* __restrict__ rinv_arr,
    float* __restrict__ alpha)
{
    const int e = blockIdx.x * 256 + threadIdx.x;
    if (e >= NE) return;
    const int d = ei[e];
    const int s = ei[NE + e];
    float h = s_dst[d] + s_src[s] + a_b[0];
    h = (h >= 0.f) ? h : LRELU * h;
    alpha[e] = expf(h) * rinv_arr[d];
}

// ---------------------------------------------------------------------------
extern "C" void kernel_launch(void* const* d_in, const int* in_sizes, int n_in,
                              void* d_out, int out_size, void* d_ws, size_t ws_size,
                              hipStream_t stream) {
    const float* x   = (const float*)d_in[0];
    const int*   ei  = (const int*)d_in[1];   // [2*E]: row0 = dst, row1 = src
    const float* W   = (const float*)d_in[2];
    const float* a_w = (const float*)d_in[3];
    const float* a_b = (const float*)d_in[4];

    float* out   = (float*)d_out;                     // [N*64]
    float* alpha = out + (size_t)NN * NH;             // [E]

    // workspace layout (~12 MB)
    __hip_bfloat16* z16 = (__hip_bfloat16*)d_ws;          // [N*64]   6.4 MB
    __hip_bfloat16* Bt  = z16 + (size_t)NN * NH;          // [80*128] 20 KB
    float* s_dst  = (float*)(Bt + 80 * NF);               // [N]
    float* s_src  = s_dst + NN;                           // [N]
    float* rinv   = s_src + NN;                           // [N]
    int* cursor   = (int*)(rinv + NN);                    // [NB]
    unsigned* recs = (unsigned*)(cursor + NB);            // [NB*CAP] 4.4 MB

    k0_build_bt <<<80, 128, 0, stream>>>(W, a_w, Bt, cursor);
    k1_gemm     <<<(NTILES + 3) / 4, 256, 0, stream>>>(x, Bt, z16, s_dst, s_src);
    kC_partition<<<KB, 1024, 0, stream>>>(ei, cursor, recs);
    kD_aggregate<<<NB, 512, 0, stream>>>(z16, s_dst, s_src, a_b, recs, cursor, rinv, out);
    k7_alpha    <<<(NE + 255) / 256, 256, 0, stream>>>(ei, s_dst, s_src, a_b, rinv, alpha);
}

// Round 12
// 79.669 us; speedup vs baseline: 1.4517x; 1.0488x over previous
//
#include <hip/hip_runtime.h>
#include <hip/hip_bf16.h>

#define NN 50000
#define NE 800000
#define NF 128
#define NH 64
#define LRELU 0.05f
#define NTILES (NN / 16)                    // 3125 (exact)
#define SLOT 64                             // per-node capacity (max deg ~40)
#define BKT 32                              // nodes per bucket
#define NB ((NN + BKT - 1) / BKT)           // 1563 buckets
#define CAP 704                             // per-bucket capacity (load ~512+8.5 sigma)
#define KB 256                              // partition blocks (1 per CU)
#define EPB (NE / KB)                       // 3125 edges per block (exact)

typedef __attribute__((ext_vector_type(8))) short bf16x8;  // 8 bf16 = 4 VGPR
typedef __attribute__((ext_vector_type(4))) float f32x4;
typedef __attribute__((ext_vector_type(4))) unsigned int u32x4;

static __device__ inline short f2bf(float f) {
    __hip_bfloat16 h = __float2bfloat16(f);
    return *reinterpret_cast<short*>(&h);
}

// ---------------------------------------------------------------------------
// K0: Bt[80][128] bf16: rows 0..63 = W^T, 64 = (W@a1)^T, 65 = (W@a2)^T, pad 0.
// Also zeroes the per-bucket cursor array (10240 threads >= NB).
// ---------------------------------------------------------------------------
__global__ __launch_bounds__(128) void k0_build_bt(
    const float* __restrict__ W, const float* __restrict__ a_w,
    __hip_bfloat16* __restrict__ Bt, int* __restrict__ cursor)
{
    const int c = blockIdx.x, k = threadIdx.x;
    const int gid = c * 128 + k;
    if (gid < NB) cursor[gid] = 0;

    float v = 0.f;
    if (c < NH) {
        v = W[k * NH + c];
    } else if (c == NH) {
        #pragma unroll 8
        for (int h = 0; h < NH; ++h) v = fmaf(W[k * NH + h], a_w[h], v);
    } else if (c == NH + 1) {
        #pragma unroll 8
        for (int h = 0; h < NH; ++h) v = fmaf(W[k * NH + h], a_w[NH + h], v);
    }
    Bt[c * NF + k] = __float2bfloat16(v);
}

// ---------------------------------------------------------------------------
// K1: MFMA GEMM: [z16 | s_dst | s_src] = x @ Bt^T. 1 wave = 16 rows x 80 cols.
// ---------------------------------------------------------------------------
__global__ __launch_bounds__(256) void k1_gemm(
    const float* __restrict__ x, const __hip_bfloat16* __restrict__ Bt,
    __hip_bfloat16* __restrict__ z16,
    float* __restrict__ s_dst, float* __restrict__ s_src)
{
    const int wave = threadIdx.x >> 6, lane = threadIdx.x & 63;
    const int tile = blockIdx.x * 4 + wave;
    if (tile >= NTILES) return;
    const int r0   = tile * 16;
    const int lrow = lane & 15;
    const int lgrp = lane >> 4;

    bf16x8 bfrag[5][4];
    #pragma unroll
    for (int n = 0; n < 5; ++n)
        #pragma unroll
        for (int t = 0; t < 4; ++t)
            bfrag[n][t] = *(const bf16x8*)&Bt[(n * 16 + lrow) * NF + t * 32 + lgrp * 8];

    bf16x8 afrag[4];
    const float* xrow = x + (size_t)(r0 + lrow) * NF + lgrp * 8;
    #pragma unroll
    for (int t = 0; t < 4; ++t) {
        f32x4 u = *(const f32x4*)(xrow + t * 32);
        f32x4 v = *(const f32x4*)(xrow + t * 32 + 4);
        bf16x8 a;
        #pragma unroll
        for (int j = 0; j < 4; ++j) { a[j] = f2bf(u[j]); a[4 + j] = f2bf(v[j]); }
        afrag[t] = a;
    }

    f32x4 acc[5] = {};
    #pragma unroll
    for (int t = 0; t < 4; ++t)
        #pragma unroll
        for (int n = 0; n < 5; ++n)
            acc[n] = __builtin_amdgcn_mfma_f32_16x16x32_bf16(afrag[t], bfrag[n][t], acc[n], 0, 0, 0);

    #pragma unroll
    for (int n = 0; n < 4; ++n)
        #pragma unroll
        for (int r = 0; r < 4; ++r)
            z16[(size_t)(r0 + lgrp * 4 + r) * NH + n * 16 + lrow] = __float2bfloat16(acc[n][r]);

    #pragma unroll
    for (int r = 0; r < 4; ++r) {
        const int orow = r0 + lgrp * 4 + r;
        if (lrow == 0)      s_dst[orow] = acc[4][r];
        else if (lrow == 1) s_src[orow] = acc[4][r];
    }
}

// ---------------------------------------------------------------------------
// KC: single-pass partition, 256 blocks (1/CU). Read each edge ONCE; the LDS
// histogram atomicAdd returns the in-block rank; edge data held in registers
// (4 statically-indexed slots). Then one global atomicAdd per nonzero
// (block,bucket) reserves a range, and records are scattered from registers.
// ---------------------------------------------------------------------------
__global__ __launch_bounds__(1024) void kC_partition(
    const int* __restrict__ ei, int* __restrict__ cursor,
    unsigned* __restrict__ recs)
{
    __shared__ unsigned hist[NB];    // 6.25 KB
    __shared__ unsigned basel[NB];   // 6.25 KB
    const int tid = threadIdx.x;
    for (int i = tid; i < NB; i += 1024) hist[i] = 0;
    __syncthreads();

    const int base = blockIdx.x * EPB;
    int      bb0 = -1, bb1 = -1, bb2 = -1, bb3 = -1;
    unsigned rk0 = 0, rk1 = 0, rk2 = 0, rk3 = 0;
    unsigned pl0 = 0, pl1 = 0, pl2 = 0, pl3 = 0;

    #define KC_GRAB(J, BBJ, RKJ, PLJ)                                          \
        { const int i = tid + (J) * 1024;                                      \
          if (i < EPB) {                                                       \
              const int d = ei[base + i];                                      \
              const int s = ei[NE + base + i];                                 \
              BBJ = d >> 5;                                                    \
              RKJ = atomicAdd(&hist[BBJ], 1u);                                 \
              PLJ = (unsigned)s | ((unsigned)(d & 31) << 16);                  \
          } }
    KC_GRAB(0, bb0, rk0, pl0)
    KC_GRAB(1, bb1, rk1, pl1)
    KC_GRAB(2, bb2, rk2, pl2)
    KC_GRAB(3, bb3, rk3, pl3)
    #undef KC_GRAB
    __syncthreads();

    for (int b = tid; b < NB; b += 1024) {
        const unsigned c = hist[b];
        basel[b] = c ? (unsigned)atomicAdd(&cursor[b], (int)c) : 0u;
    }
    __syncthreads();

    #define KC_PUT(BBJ, RKJ, PLJ)                                              \
        if (BBJ >= 0) {                                                        \
            const unsigned pos = basel[BBJ] + RKJ;                             \
            if (pos < CAP) recs[(size_t)BBJ * CAP + pos] = PLJ;                \
        }
    KC_PUT(bb0, rk0, pl0)
    KC_PUT(bb1, rk1, pl1)
    KC_PUT(bb2, rk2, pl2)
    KC_PUT(bb3, rk3, pl3)
    #undef KC_PUT
}

// ---------------------------------------------------------------------------
// KD: one block (512 thr) per bucket (32 nodes). Stage: read recs (coalesced),
// h = exp(lrelu(sd+ss+b)), bin {src,bf16(h)} into LDS. Aggregate: per-wave
// wide z-gathers (8 lanes x dwordx4 per row = 8 edges per load); out + rinv.
// ---------------------------------------------------------------------------
__global__ __launch_bounds__(512) void kD_aggregate(
    const __hip_bfloat16* __restrict__ z16,
    const float* __restrict__ s_dst, const float* __restrict__ s_src,
    const float* __restrict__ a_b,
    const unsigned* __restrict__ recs, const int* __restrict__ cursor,
    float* __restrict__ rinv_arr, float* __restrict__ out)
{
    __shared__ unsigned bins[BKT * SLOT];   // 8 KB
    __shared__ unsigned lcnt[BKT];
    __shared__ float    sdl[BKT];
    const int bkt = blockIdx.x;
    const int tid = threadIdx.x;
    const int n0  = bkt * BKT;

    if (tid < BKT) {
        lcnt[tid] = 0;
        sdl[tid] = (n0 + tid < NN) ? s_dst[n0 + tid] : 0.f;
    }
    __syncthreads();

    int tot = cursor[bkt];
    if (tot > CAP) tot = CAP;
    const float bias = a_b[0];

    for (int i = tid; i < tot; i += 512) {
        const unsigned rec = recs[(size_t)bkt * CAP + i];
        const unsigned src = rec & 0xffffu;
        const unsigned dl  = (rec >> 16) & 31u;
        float h = sdl[dl] + s_src[src] + bias;
        h = (h >= 0.f) ? h : LRELU * h;
        h = expf(h);
        const unsigned r = atomicAdd(&lcnt[dl], 1u);
        if (r < SLOT)
            bins[dl * SLOT + r] = src | ((unsigned)(unsigned short)f2bf(h) << 16);
    }
    __syncthreads();

    const int wave = tid >> 6, lane = tid & 63;
    const int sub  = lane >> 3, col8 = lane & 7;
    const char* zb = (const char*)z16;

    for (int dl = wave; dl < BKT; dl += 8) {
        const int node = n0 + dl;
        if (node >= NN) break;
        int deg = (int)__builtin_amdgcn_readfirstlane(lcnt[dl]);
        if (deg > SLOT) deg = SLOT;

        unsigned pv = (lane < deg) ? bins[dl * SLOT + lane] : 0u;
        float hs = __uint_as_float(pv & 0xffff0000u);
        float acc[8] = {0.f, 0.f, 0.f, 0.f, 0.f, 0.f, 0.f, 0.f};

        const int gmax = (deg + 7) >> 3;
        for (int g = 0; g < gmax; ++g) {
            const unsigned pg = (unsigned)__builtin_amdgcn_ds_bpermute(
                ((g << 3) | sub) << 2, (int)pv);
            const float hg = __uint_as_float(pg & 0xffff0000u);
            const unsigned sg = pg & 0xffffu;
            const u32x4 q = *(const u32x4*)(zb + ((size_t)(sg << 7) | (col8 << 4)));
            #pragma unroll
            for (int i = 0; i < 4; ++i) {
                acc[2*i]   = fmaf(hg, __uint_as_float(q[i] << 16),         acc[2*i]);
                acc[2*i+1] = fmaf(hg, __uint_as_float(q[i] & 0xffff0000u), acc[2*i+1]);
            }
        }

        #pragma unroll
        for (int off = 8; off <= 32; off <<= 1)
            #pragma unroll
            for (int i = 0; i < 8; ++i) acc[i] += __shfl_xor(acc[i], off, 64);

        #pragma unroll
        for (int off = 32; off > 0; off >>= 1) hs += __shfl_xor(hs, off, 64);
        const float rinv = (deg > 0) ? 1.f / hs : 0.f;
        if (lane == 0) rinv_arr[node] = rinv;

        if (lane < 8) {
            f32x4 o0 = {acc[0] * rinv, acc[1] * rinv, acc[2] * rinv, acc[3] * rinv};
            f32x4 o1 = {acc[4] * rinv, acc[5] * rinv, acc[6] * rinv, acc[7] * rinv};
            float* op = out + (size_t)node * NH + lane * 8;
            *(f32x4*)op       = o0;
            *(f32x4*)(op + 4) = o1;
        }
    }
}

// ---------------------------------------------------------------------------
// K7: alpha[e] = exp(lrelu(sd+ss+b)) * rinv[dst] — f32-exact h, coalesced
// write; 3 small L2-resident gathers per edge.
// ---------------------------------------------------------------------------
__global__ __launch_bounds__(256) void k7_alpha(
    const int* __restrict__ ei,
    const float* __restrict__ s_dst, const float* __restrict__ s_src,
    const float* __restrict__ a_b, const float* __restrict__ rinv_arr,
    float* __restrict__ alpha)
{
    const int e = blockIdx.x * 256 + threadIdx.x;
    if (e >= NE) return;
    const int d = ei[e];
    const int s = ei[NE + e];
    float h = s_dst[d] + s_src[s] + a_b[0];
    h = (h >= 0.f) ? h : LRELU * h;
    alpha[e] = expf(h) * rinv_arr[d];
}

// ---------------------------------------------------------------------------
extern "C" void kernel_launch(void* const* d_in, const int* in_sizes, int n_in,
                              void* d_out, int out_size, void* d_ws, size_t ws_size,
                              hipStream_t stream) {
    const float* x   = (const float*)d_in[0];
    const int*   ei  = (const int*)d_in[1];   // [2*E]: row0 = dst, row1 = src
    const float* W   = (const float*)d_in[2];
    const float* a_w = (const float*)d_in[3];
    const float* a_b = (const float*)d_in[4];

    float* out   = (float*)d_out;                     // [N*64]
    float* alpha = out + (size_t)NN * NH;             // [E]

    // workspace layout (~12 MB)
    __hip_bfloat16* z16 = (__hip_bfloat16*)d_ws;          // [N*64]   6.4 MB
    __hip_bfloat16* Bt  = z16 + (size_t)NN * NH;          // [80*128] 20 KB
    float* s_dst  = (float*)(Bt + 80 * NF);               // [N]
    float* s_src  = s_dst + NN;                           // [N]
    float* rinv   = s_src + NN;                           // [N]
    int* cursor   = (int*)(rinv + NN);                    // [NB]
    unsigned* recs = (unsigned*)(cursor + NB);            // [NB*CAP] 4.4 MB

    k0_build_bt <<<80, 128, 0, stream>>>(W, a_w, Bt, cursor);
    k1_gemm     <<<(NTILES + 3) / 4, 256, 0, stream>>>(x, Bt, z16, s_dst, s_src);
    kC_partition<<<KB, 1024, 0, stream>>>(ei, cursor, recs);
    kD_aggregate<<<NB, 512, 0, stream>>>(z16, s_dst, s_src, a_b, recs, cursor, rinv, out);
    k7_alpha    <<<(NE + 255) / 256, 256, 0, stream>>>(ei, s_dst, s_src, a_b, rinv, alpha);
}

// Round 13
// 73.585 us; speedup vs baseline: 1.5717x; 1.0827x over previous
//
#include <hip/hip_runtime.h>
#include <hip/hip_bf16.h>

#define NN 50000
#define NE 800000
#define NF 128
#define NH 64
#define LRELU 0.05f
#define NTILES (NN / 16)                    // 3125 (exact)
#define GEMM_BLKS ((NTILES + 7) / 8)        // 391 blocks x 8 waves
#define SLOT 64                             // per-node capacity (max deg ~40)
#define BKT 32                              // nodes per bucket
#define NB ((NN + BKT - 1) / BKT)           // 1563 buckets
#define CAP 704                             // per-bucket capacity (load ~512+8.5 sigma)
#define KB 400                              // partition blocks
#define EPB (NE / KB)                       // 2000 edges per block (exact)

typedef __attribute__((ext_vector_type(8))) short bf16x8;  // 8 bf16 = 4 VGPR
typedef __attribute__((ext_vector_type(4))) float f32x4;
typedef __attribute__((ext_vector_type(4))) unsigned int u32x4;

static __device__ inline short f2bf(float f) {
    __hip_bfloat16 h = __float2bfloat16(f);
    return *reinterpret_cast<short*>(&h);
}

// ---------------------------------------------------------------------------
// K0: Bt[80][128] bf16: rows 0..63 = W^T, 64 = (W@a1)^T, 65 = (W@a2)^T, pad 0.
// Also zeroes the per-bucket cursor array (10240 threads >= NB).
// ---------------------------------------------------------------------------
__global__ __launch_bounds__(128) void k0_build_bt(
    const float* __restrict__ W, const float* __restrict__ a_w,
    __hip_bfloat16* __restrict__ Bt, int* __restrict__ cursor)
{
    const int c = blockIdx.x, k = threadIdx.x;
    const int gid = c * 128 + k;
    if (gid < NB) cursor[gid] = 0;

    float v = 0.f;
    if (c < NH) {
        v = W[k * NH + c];
    } else if (c == NH) {
        #pragma unroll 8
        for (int h = 0; h < NH; ++h) v = fmaf(W[k * NH + h], a_w[h], v);
    } else if (c == NH + 1) {
        #pragma unroll 8
        for (int h = 0; h < NH; ++h) v = fmaf(W[k * NH + h], a_w[NH + h], v);
    }
    Bt[c * NF + k] = __float2bfloat16(v);
}

// ---------------------------------------------------------------------------
// FAT: two independent roles selected by blockIdx (concurrent on the device):
//  - blocks [0, GEMM_BLKS):  MFMA GEMM [z16|s_dst|s_src] = x @ Bt^T,
//    8 waves/block, 1 wave = 16 rows x 80 cols; bfrags loaded in-loop
//    (each is used exactly once -> no register hoarding).
//  - blocks [GEMM_BLKS, +KB): single-pass edge partition: LDS histogram
//    returns in-block rank; one global atomicAdd per nonzero (block,bucket)
//    reserves a range; records scattered from registers.
// ---------------------------------------------------------------------------
__global__ __launch_bounds__(512, 2) void k_fat(
    const float* __restrict__ x, const __hip_bfloat16* __restrict__ Bt,
    __hip_bfloat16* __restrict__ z16,
    float* __restrict__ s_dst, float* __restrict__ s_src,
    const int* __restrict__ ei, int* __restrict__ cursor,
    unsigned* __restrict__ recs)
{
    __shared__ unsigned hist[NB];    // 6.25 KB (partition role only)
    __shared__ unsigned basel[NB];   // 6.25 KB
    const int tid = threadIdx.x;

    if (blockIdx.x < GEMM_BLKS) {
        // ----- GEMM role -----
        const int wave = tid >> 6, lane = tid & 63;
        const int tile = blockIdx.x * 8 + wave;
        if (tile >= NTILES) return;
        const int r0   = tile * 16;
        const int lrow = lane & 15;
        const int lgrp = lane >> 4;

        bf16x8 afrag[4];
        const float* xrow = x + (size_t)(r0 + lrow) * NF + lgrp * 8;
        #pragma unroll
        for (int t = 0; t < 4; ++t) {
            f32x4 u = *(const f32x4*)(xrow + t * 32);
            f32x4 v = *(const f32x4*)(xrow + t * 32 + 4);
            bf16x8 a;
            #pragma unroll
            for (int j = 0; j < 4; ++j) { a[j] = f2bf(u[j]); a[4 + j] = f2bf(v[j]); }
            afrag[t] = a;
        }

        f32x4 acc[5] = {};
        #pragma unroll
        for (int t = 0; t < 4; ++t)
            #pragma unroll
            for (int n = 0; n < 5; ++n) {
                const bf16x8 b = *(const bf16x8*)&Bt[(n * 16 + lrow) * NF + t * 32 + lgrp * 8];
                acc[n] = __builtin_amdgcn_mfma_f32_16x16x32_bf16(afrag[t], b, acc[n], 0, 0, 0);
            }

        #pragma unroll
        for (int n = 0; n < 4; ++n)
            #pragma unroll
            for (int r = 0; r < 4; ++r)
                z16[(size_t)(r0 + lgrp * 4 + r) * NH + n * 16 + lrow] = __float2bfloat16(acc[n][r]);

        #pragma unroll
        for (int r = 0; r < 4; ++r) {
            const int orow = r0 + lgrp * 4 + r;
            if (lrow == 0)      s_dst[orow] = acc[4][r];
            else if (lrow == 1) s_src[orow] = acc[4][r];
        }
    } else {
        // ----- Partition role -----
        const int pb = blockIdx.x - GEMM_BLKS;
        for (int i = tid; i < NB; i += 512) hist[i] = 0;
        __syncthreads();

        const int base = pb * EPB;
        int      bb0 = -1, bb1 = -1, bb2 = -1, bb3 = -1;
        unsigned rk0 = 0, rk1 = 0, rk2 = 0, rk3 = 0;
        unsigned pl0 = 0, pl1 = 0, pl2 = 0, pl3 = 0;

        #define KC_GRAB(J, BBJ, RKJ, PLJ)                                      \
            { const int i = tid + (J) * 512;                                   \
              if (i < EPB) {                                                   \
                  const int d = ei[base + i];                                  \
                  const int s = ei[NE + base + i];                             \
                  BBJ = d >> 5;                                                \
                  RKJ = atomicAdd(&hist[BBJ], 1u);                             \
                  PLJ = (unsigned)s | ((unsigned)(d & 31) << 16);              \
              } }
        KC_GRAB(0, bb0, rk0, pl0)
        KC_GRAB(1, bb1, rk1, pl1)
        KC_GRAB(2, bb2, rk2, pl2)
        KC_GRAB(3, bb3, rk3, pl3)
        #undef KC_GRAB
        __syncthreads();

        for (int b = tid; b < NB; b += 512) {
            const unsigned c = hist[b];
            basel[b] = c ? (unsigned)atomicAdd(&cursor[b], (int)c) : 0u;
        }
        __syncthreads();

        #define KC_PUT(BBJ, RKJ, PLJ)                                          \
            if (BBJ >= 0) {                                                    \
                const unsigned pos = basel[BBJ] + RKJ;                         \
                if (pos < CAP) recs[(size_t)BBJ * CAP + pos] = PLJ;            \
            }
        KC_PUT(bb0, rk0, pl0)
        KC_PUT(bb1, rk1, pl1)
        KC_PUT(bb2, rk2, pl2)
        KC_PUT(bb3, rk3, pl3)
        #undef KC_PUT
    }
}

// ---------------------------------------------------------------------------
// KD: one block (512 thr) per bucket (32 nodes). Stage: read recs (coalesced),
// h = exp(lrelu(sd+ss+b)), bin {src,bf16(h)} into LDS. Aggregate: per-wave
// wide z-gathers (8 lanes x dwordx4 per row = 8 edges per load); out + rinv.
// ---------------------------------------------------------------------------
__global__ __launch_bounds__(512) void kD_aggregate(
    const __hip_bfloat16* __restrict__ z16,
    const float* __restrict__ s_dst, const float* __restrict__ s_src,
    const float* __restrict__ a_b,
    const unsigned* __restrict__ recs, const int* __restrict__ cursor,
    float* __restrict__ rinv_arr, float* __restrict__ out)
{
    __shared__ unsigned bins[BKT * SLOT];   // 8 KB
    __shared__ unsigned lcnt[BKT];
    __shared__ float    sdl[BKT];
    const int bkt = blockIdx.x;
    const int tid = threadIdx.x;
    const int n0  = bkt * BKT;

    if (tid < BKT) {
        lcnt[tid] = 0;
        sdl[tid] = (n0 + tid < NN) ? s_dst[n0 + tid] : 0.f;
    }
    __syncthreads();

    int tot = cursor[bkt];
    if (tot > CAP) tot = CAP;
    const float bias = a_b[0];

    for (int i = tid; i < tot; i += 512) {
        const unsigned rec = recs[(size_t)bkt * CAP + i];
        const unsigned src = rec & 0xffffu;
        const unsigned dl  = (rec >> 16) & 31u;
        float h = sdl[dl] + s_src[src] + bias;
        h = (h >= 0.f) ? h : LRELU * h;
        h = expf(h);
        const unsigned r = atomicAdd(&lcnt[dl], 1u);
        if (r < SLOT)
            bins[dl * SLOT + r] = src | ((unsigned)(unsigned short)f2bf(h) << 16);
    }
    __syncthreads();

    const int wave = tid >> 6, lane = tid & 63;
    const int sub  = lane >> 3, col8 = lane & 7;
    const char* zb = (const char*)z16;

    for (int dl = wave; dl < BKT; dl += 8) {
        const int node = n0 + dl;
        if (node >= NN) break;
        int deg = (int)__builtin_amdgcn_readfirstlane(lcnt[dl]);
        if (deg > SLOT) deg = SLOT;

        unsigned pv = (lane < deg) ? bins[dl * SLOT + lane] : 0u;
        float hs = __uint_as_float(pv & 0xffff0000u);
        float acc[8] = {0.f, 0.f, 0.f, 0.f, 0.f, 0.f, 0.f, 0.f};

        const int gmax = (deg + 7) >> 3;
        for (int g = 0; g < gmax; ++g) {
            const unsigned pg = (unsigned)__builtin_amdgcn_ds_bpermute(
                ((g << 3) | sub) << 2, (int)pv);
            const float hg = __uint_as_float(pg & 0xffff0000u);
            const unsigned sg = pg & 0xffffu;
            const u32x4 q = *(const u32x4*)(zb + ((size_t)(sg << 7) | (col8 << 4)));
            #pragma unroll
            for (int i = 0; i < 4; ++i) {
                acc[2*i]   = fmaf(hg, __uint_as_float(q[i] << 16),         acc[2*i]);
                acc[2*i+1] = fmaf(hg, __uint_as_float(q[i] & 0xffff0000u), acc[2*i+1]);
            }
        }

        #pragma unroll
        for (int off = 8; off <= 32; off <<= 1)
            #pragma unroll
            for (int i = 0; i < 8; ++i) acc[i] += __shfl_xor(acc[i], off, 64);

        #pragma unroll
        for (int off = 32; off > 0; off >>= 1) hs += __shfl_xor(hs, off, 64);
        const float rinv = (deg > 0) ? 1.f / hs : 0.f;
        if (lane == 0) rinv_arr[node] = rinv;

        if (lane < 8) {
            f32x4 o0 = {acc[0] * rinv, acc[1] * rinv, acc[2] * rinv, acc[3] * rinv};
            f32x4 o1 = {acc[4] * rinv, acc[5] * rinv, acc[6] * rinv, acc[7] * rinv};
            float* op = out + (size_t)node * NH + lane * 8;
            *(f32x4*)op       = o0;
            *(f32x4*)(op + 4) = o1;
        }
    }
}

// ---------------------------------------------------------------------------
// K7: alpha[e] = exp(lrelu(sd+ss+b)) * rinv[dst] — f32-exact h, coalesced
// write; 3 small L2-resident gathers per edge.
// ---------------------------------------------------------------------------
__global__ __launch_bounds__(256) void k7_alpha(
    const int* __restrict__ ei,
    const float* __restrict__ s_dst, const float* __restrict__ s_src,
    const float* __restrict__ a_b, const float* __restrict__ rinv_arr,
    float* __restrict__ alpha)
{
    const int e = blockIdx.x * 256 + threadIdx.x;
    if (e >= NE) return;
    const int d = ei[e];
    const int s = ei[NE + e];
    float h = s_dst[d] + s_src[s] + a_b[0];
    h = (h >= 0.f) ? h : LRELU * h;
    alpha[e] = expf(h) * rinv_arr[d];
}

// ---------------------------------------------------------------------------
extern "C" void kernel_launch(void* const* d_in, const int* in_sizes, int n_in,
                              void* d_out, int out_size, void* d_ws, size_t ws_size,
                              hipStream_t stream) {
    const float* x   = (const float*)d_in[0];
    const int*   ei  = (const int*)d_in[1];   // [2*E]: row0 = dst, row1 = src
    const float* W   = (const float*)d_in[2];
    const float* a_w = (const float*)d_in[3];
    const float* a_b = (const float*)d_in[4];

    float* out   = (float*)d_out;                     // [N*64]
    float* alpha = out + (size_t)NN * NH;             // [E]

    // workspace layout (~12 MB)
    __hip_bfloat16* z16 = (__hip_bfloat16*)d_ws;          // [N*64]   6.4 MB
    __hip_bfloat16* Bt  = z16 + (size_t)NN * NH;          // [80*128] 20 KB
    float* s_dst  = (float*)(Bt + 80 * NF);               // [N]
    float* s_src  = s_dst + NN;                           // [N]
    float* rinv   = s_src + NN;                           // [N]
    int* cursor   = (int*)(rinv + NN);                    // [NB]
    unsigned* recs = (unsigned*)(cursor + NB);            // [NB*CAP] 4.4 MB

    k0_build_bt <<<80, 128, 0, stream>>>(W, a_w, Bt, cursor);
    k_fat       <<<GEMM_BLKS + KB, 512, 0, stream>>>(x, Bt, z16, s_dst, s_src, ei, cursor, recs);
    kD_aggregate<<<NB, 512, 0, stream>>>(z16, s_dst, s_src, a_b, recs, cursor, rinv, out);
    k7_alpha    <<<(NE + 255) / 256, 256, 0, stream>>>(ei, s_dst, s_src, a_b, rinv, alpha);
}